// Round 2
// baseline (95.585 us; speedup 1.0000x reference)
//
#include <hip/hip_runtime.h>

// Overlapped-chunk HMM forward filter, all-VALU inner loop.
// CHUNK_L=32, WARMUP_W=16 -> 15625 chunks, ~3.8 waves/SIMD, work 1.5x T.
// R6 changes (theory: kernel portion ~40us is y-cold-load latency-bound, not
// issue-bound (~7us) nor chain-bound (~1us)):
//  1) y software pipeline deepened 2->4 blocks (16 steps of issue >= ~900cyc
//     HBM latency); chunk's first 4 y loads hoisted ABOVE the pi-squaring
//     preamble so the cold first-touch hides under ~10 barrier rounds.
//  2) carry chain is now PURE dot16->mul: carry raw pg3; the rescale r1
//     (ready 2.5 steps earlier) folds into the NEXT block's first emission
//     factor off-chain. Entry scale stays bounded (= f2*f3 of prev block;
//     <=6-f exposure, same as warm-up already tolerates). First-step outputs
//     use r3_prev (ut0 = q0*r3p) and w = s1*r3 (ft0 = s0*w), both off-chain.
//  3) warm-up mid renorm folded the same way (rw into block-2 emission).
// (R7: identical resubmission — R6 bench died to container acquire failure,
//  no kernel verdict was produced.)
#define CHUNK_L 32
#define WARMUP_W 16

typedef float v2f __attribute__((ext_vector_type(2)));

template<int K> __device__ __forceinline__ float bcast16(float v) {
    // broadcast lane (row_start + K) across the 16-lane row (row_newbcast)
    return __int_as_float(__builtin_amdgcn_update_dpp(
        0, __float_as_int(v), 0x150 | K, 0xF, 0xF, true));
}
template<int N> __device__ __forceinline__ float rowror16(float v) {
    return __int_as_float(__builtin_amdgcn_update_dpp(
        0, __float_as_int(v), 0x120 | N, 0xF, 0xF, true));
}

__device__ __forceinline__ float rowsum16(float p) {
    p += rowror16<1>(p);
    p += rowror16<2>(p);
    p += rowror16<4>(p);
    p += rowror16<8>(p);
    return p;
}

// (a @ P)_j : 16 DPP broadcasts + 8 v_pk_fma_f32 (2 indep accumulator pairs)
__device__ __forceinline__ float dot16(float a, const v2f* pc2) {
    v2f b0, b1, u01, u23;
    b0.x = bcast16<0>(a);  b0.y = bcast16<1>(a);
    b1.x = bcast16<2>(a);  b1.y = bcast16<3>(a);
    u01 = b0 * pc2[0];
    u23 = b1 * pc2[1];
    b0.x = bcast16<4>(a);  b0.y = bcast16<5>(a);
    b1.x = bcast16<6>(a);  b1.y = bcast16<7>(a);
    u01 = b0 * pc2[2] + u01;
    u23 = b1 * pc2[3] + u23;
    b0.x = bcast16<8>(a);  b0.y = bcast16<9>(a);
    b1.x = bcast16<10>(a); b1.y = bcast16<11>(a);
    u01 = b0 * pc2[4] + u01;
    u23 = b1 * pc2[5] + u23;
    b0.x = bcast16<12>(a); b0.y = bcast16<13>(a);
    b1.x = bcast16<14>(a); b1.y = bcast16<15>(a);
    u01 = b0 * pc2[6] + u01;
    u23 = b1 * pc2[7] + u23;
    v2f u = u01 + u23;
    return u.x + u.y;
}

__global__ __launch_bounds__(256, 4) void hmm_filter_kernel(
    const float* __restrict__ y,
    const float* __restrict__ logits,
    const float* __restrict__ mu,
    const float* __restrict__ log_sigma,
    float* __restrict__ out,
    int T, int nchunks)
{
    __shared__ float Plds[256];
    __shared__ float Ba[256];
    __shared__ float Bb[256];

    const int tid = (int)threadIdx.x;
    const int j   = tid & 15;     // state / column index
    const int g   = tid >> 4;     // row (preamble) / group id (main)

    // ---- P = softmax(logits, axis=-1) ----
    float l = logits[tid];
    float m = l;
    #pragma unroll
    for (int s = 1; s < 16; s <<= 1) m = fmaxf(m, __shfl_xor(m, s, 16));
    float e = __expf(l - m);
    float rs = e;
    #pragma unroll
    for (int s = 1; s < 16; s <<= 1) rs += __shfl_xor(rs, s, 16);
    float Pv = e / rs;
    Plds[tid] = Pv;
    Ba[tid]   = Pv;

    // ---- chunk geometry + HOISTED y prefetch (hides cold-miss latency
    //      under the pi-squaring preamble's ~10 barrier rounds) ----
    const int chunk = (int)blockIdx.x * 16 + g;
    const int wfrom = chunk * CHUNK_L;
    int t0 = wfrom - WARMUP_W; if (t0 < 0) t0 = 0;  // chunk 0: EXACT from t=0
    const int Tm4 = T - 4;
    int ta = t0; if (ta > Tm4) ta = Tm4;            // OOB-group clamp (safe)
    int a1 = ta + 4;  if (a1 > Tm4) a1 = Tm4;
    int a2 = ta + 8;  if (a2 > Tm4) a2 = Tm4;
    int a3 = ta + 12; if (a3 > Tm4) a3 = Tm4;
    float4 c4 = *(const float4*)(y + ta);
    float4 n1 = *(const float4*)(y + a1);
    float4 n2 = *(const float4*)(y + a2);
    float4 n3 = *(const float4*)(y + a3);

    __syncthreads();

    // ---- stationary pi: P^(2^10) via renormalized squaring (cold) ----
    float* cur = Ba;
    float* nxt = Bb;
    for (int itq = 0; itq < 10; ++itq) {
        float acc = 0.f;
        #pragma unroll
        for (int k = 0; k < 16; ++k)
            acc += cur[g * 16 + k] * cur[k * 16 + j];
        float rsum = acc;
        #pragma unroll
        for (int s = 1; s < 16; s <<= 1) rsum += __shfl_xor(rsum, s, 16);
        nxt[tid] = acc / rsum;
        __syncthreads();
        float* tmp = cur; cur = nxt; nxt = tmp;
    }
    // no barriers below this point (early return is safe)

    const float api = cur[j];                 // pi_j

    // P column j as 8 float2 pairs (k ascending)
    v2f pc2[8];
    #pragma unroll
    for (int k = 0; k < 8; ++k) {
        pc2[k].x = Plds[(2 * k)     * 16 + j];
        pc2[k].y = Plds[(2 * k + 1) * 16 + j];
    }

    const float muj = mu[j];
    const float isj = __expf(-log_sigma[j]);              // 1/sigma_j
    const float nmj = -muj * isj;                         // z = fma(y, isj, nmj)
    const float lcf = __log2f(0.3989422804014327f * isj); // log2(coef)
    const float K2  = -0.7213475204444817f;               // -0.5*log2(e)
    // g_j(y) = exp2( fma(z*z, K2, lcf) )

    if (chunk >= nchunks) return;

    const int nwb = (wfrom - t0) >> 2;              // warm 4-blocks: 0 or 4
    const int TN  = T << 4;

    // emission density (single v_exp_f32)
    auto emis = [&](float yt) -> float {
        float z = fmaf(yt, isj, nmj);
        return __builtin_amdgcn_exp2f(fmaf(z * z, K2, lcf));
    };

    float p = api;   // carried (unnormalized) filtrate
    int t = t0;

    // ---- warm-up: pure dot->mul chain; mid renorm folded into the next
    //      block's first emission (off-chain) ----
    float rw = 1.f;
    for (int b = 0; b < nwb; ++b) {
        int p4 = t + 16; if (p4 > Tm4) p4 = Tm4;
        const float4 nn = *(const float4*)(y + p4);
        float e0w = emis(c4.x);
        if (b == 2) e0w *= rw;                   // folded mid renorm
        p = dot16(p, pc2) * e0w;
        p = dot16(p, pc2) * emis(c4.y);
        p = dot16(p, pc2) * emis(c4.z);
        p = dot16(p, pc2) * emis(c4.w);
        if (b == 1) rw = __builtin_amdgcn_rcpf(rowsum16(p));  // ~1 step slack
        c4 = n1; n1 = n2; n2 = n3; n3 = nn; t += 4;
    }
    // entering-scale reciprocal (off-chain; sum(utt)=1 => rowsum(p) = scale)
    const float rcm = __builtin_amdgcn_rcpf(rowsum16(p));

    // ---- main chunk: 8 blocks of 4 steps ----
    // Carried across blocks: r1p (folds into e0), r3p (= 1/entry-scale),
    // w (= 1/(entry-scale * r1p)). First block: r1p=r3p=rcm, w=1.
    float* __restrict__ pU = out + (wfrom << 4) + j;   // ut
    float* __restrict__ pN = pU + TN;                  // u_norm
    float* __restrict__ pF = out + 2 * TN + wfrom;     // ft (lane j==0)

    float r1p = rcm;
    float r3p = rcm;
    float w   = 1.f;

    #pragma unroll 1
    for (int b = 0; b < (CHUNK_L / 4); ++b) {
        int p4 = t + 16; if (p4 > Tm4) p4 = Tm4;
        const float4 nn = *(const float4*)(y + p4);

        // emissions (off-chain; e0 absorbs the rescale of the carried p)
        const float e0 = emis(c4.x) * r1p;

        // serial chain: dot -> mul -> dot -> mul ... (nothing else on it)
        const float q0  = dot16(p, pc2);
        const float pg0 = q0 * e0;
        const float q1  = dot16(pg0, pc2);
        const float pg1 = q1 * emis(c4.y);
        const float q2  = dot16(pg1, pc2);
        const float pg2 = q2 * emis(c4.z);
        const float q3  = dot16(pg2, pc2);
        const float pg3 = q3 * emis(c4.w);

        // normalizers (all off the serial chain)
        const float s0 = rowsum16(pg0);
        const float r0 = __builtin_amdgcn_rcpf(s0);
        const float s1 = rowsum16(pg1);
        const float r1 = __builtin_amdgcn_rcpf(s1);
        const float s2 = rowsum16(pg2);
        const float r2 = __builtin_amdgcn_rcpf(s2);
        const float s3 = rowsum16(pg3);
        const float r3 = __builtin_amdgcn_rcpf(s3);

        // outputs: all scale-invariant ratios except step 0 (uses r3p, w)
        pU[0]  = q0 * r3p;
        pU[16] = q1 * r0;
        pU[32] = q2 * r1;
        pU[48] = q3 * r2;
        pN[0]  = pg0 * r0;
        pN[16] = pg1 * r1;
        pN[32] = pg2 * r2;
        pN[48] = pg3 * r3;
        if (j == 0)
            *(float4*)pF = make_float4(s0 * w, s1 * r0, s2 * r1, s3 * r2);

        // carry RAW pg3; next block's e0 applies r1 (entry scale -> f2*f3)
        p   = pg3;
        w   = s1 * r3;      // = 1/(f2*f3) = 1/(entry_scale' * r1p')
        r1p = r1;
        r3p = r3;

        pU += 64; pN += 64; pF += 4;
        c4 = n1; n1 = n2; n2 = n3; n3 = nn; t += 4;
    }
}

extern "C" void kernel_launch(void* const* d_in, const int* in_sizes, int n_in,
                              void* d_out, int out_size, void* d_ws, size_t ws_size,
                              hipStream_t stream) {
    const float* y      = (const float*)d_in[0];
    const float* logits = (const float*)d_in[1];
    const float* mu     = (const float*)d_in[2];
    const float* ls     = (const float*)d_in[3];
    float* out = (float*)d_out;
    const int T = in_sizes[0];                 // 500000 = 32 * 15625 (exact)

    const int nchunks = (T + CHUNK_L - 1) / CHUNK_L;
    const int blocks  = (nchunks + 15) / 16;
    hmm_filter_kernel<<<blocks, 256, 0, stream>>>(y, logits, mu, ls, out,
                                                  T, nchunks);
}